// Round 7
// baseline (522.387 us; speedup 1.0000x reference)
//
#include <hip/hip_runtime.h>
#include <hip/hip_bf16.h>

// Problem constants (reference: D=128, BC=64, BS=512, K=6, OV=128, B=8)
#define NB 8            // batches
#define LSEQ 32768      // BC*BS positions per batch
#define DCH 128         // channels
#define NCHUNK 1024     // 256-row chunks
#define NSUB 4096       // 64-row sub-chunks
#define NBLK 512        // B*BC conv blocks
#define PH 520          // padded rows per block (2 front + 512 + pad, rounded)
#define SCALE_F 0.08838834764831845f

typedef __bf16 bf16x8 __attribute__((ext_vector_type(8)));
typedef float f32x4 __attribute__((ext_vector_type(4)));

__device__ __forceinline__ float bf2f(unsigned short u) {
    return __uint_as_float(((unsigned)u) << 16);
}
__device__ __forceinline__ unsigned short f2bf(float f) {
    unsigned u = __float_as_uint(f);
    u += 0x7fffu + ((u >> 16) & 1u);   // round-to-nearest-even
    return (unsigned short)(u >> 16);
}

// async global->LDS DMA, 16 B per lane; LDS dest = wave-uniform base + lane*16
__device__ __forceinline__ void async_copy16(const void* gsrc, void* ldst) {
    __builtin_amdgcn_global_load_lds(
        (const __attribute__((address_space(1))) unsigned int*)gsrc,
        (__attribute__((address_space(3))) unsigned int*)ldst, 16, 0, 0);
}

// ---------------- Stage 1: logits = silu(x @ w_lw + b); per-64-row-sub max ----------------
// Column-parallel dot (LDS partials), no per-row shuffle trees.
// NOTE (R5/R6 post-mortem): reference weights are w_i = exp(l_i - cummax_i) —
// frozen at insertion, never rescaled. The cummax does NOT cancel. Keep it.
__global__ __launch_bounds__(256) void k_logits2(const float* __restrict__ x,
                                                 const float* __restrict__ w_lw,
                                                 const float* __restrict__ b_lw,
                                                 float* __restrict__ logits,
                                                 float* __restrict__ subM) {
    int chunk = blockIdx.x, t = threadIdx.x;
    int g = t & 15, rs = t >> 4;
    __shared__ float sp[256 * 17];
    __shared__ float red[256];
    float wv[8];
    #pragma unroll
    for (int e = 0; e < 8; ++e) wv[e] = w_lw[g * 8 + e];
    float bb = b_lw[0];
    size_t base = (size_t)chunk * 256 * DCH;
    for (int i = 0; i < 16; ++i) {
        int row = rs * 16 + i;
        float4 a  = *(const float4*)(x + base + (size_t)row * DCH + g * 8);
        float4 b4 = *(const float4*)(x + base + (size_t)row * DCH + g * 8 + 4);
        sp[row * 17 + g] = a.x * wv[0] + a.y * wv[1] + a.z * wv[2] + a.w * wv[3] +
                           b4.x * wv[4] + b4.y * wv[5] + b4.z * wv[6] + b4.w * wv[7];
    }
    __syncthreads();
    float s = bb;
    #pragma unroll
    for (int j = 0; j < 16; ++j) s += sp[t * 17 + j];
    float l = s / (1.f + expf(-s));          // silu
    logits[(size_t)chunk * 256 + t] = l;
    red[t] = l;
    __syncthreads();
    for (int off = 32; off >= 1; off >>= 1) {
        if ((t & 63) < off) red[t] = fmaxf(red[t], red[t + off]);
        __syncthreads();
    }
    if ((t & 63) == 0) subM[chunk * 4 + (t >> 6)] = red[t];
}

// ---------------- Stage 2: exclusive prefix-max over sub-chunks (per batch) ----------------
__global__ void k_seed_max(const float* __restrict__ subM, float* __restrict__ seedM) {
    int b = threadIdx.x;
    if (b < NB) {
        float run = -INFINITY;
        for (int s = 0; s < 512; ++s) {
            seedM[b * 512 + s] = run;
            run = fmaxf(run, subM[b * 512 + s]);
        }
    }
}

// ---------------- Stage 3: w_i = exp(l_i - max(seedM, cummax_loc)); sub sums ----------------
__global__ __launch_bounds__(256) void k_sums(const float* __restrict__ x,
                                              const float* __restrict__ logits,
                                              const float* __restrict__ seedM,
                                              float* __restrict__ exg,
                                              float* __restrict__ S_w,
                                              float* __restrict__ S_wx) {
    int chunk = blockIdx.x, t = threadIdx.x;
    int g = t & 15, rs = t >> 4;
    __shared__ float llog[256];
    __shared__ float wbuf[256];
    __shared__ float red[256];
    __shared__ float rp[16 * 130];
    llog[t] = logits[(size_t)chunk * 256 + t];
    __syncthreads();
    if (t < 4) {                                // serial 64-deep running max per sub
        float M = seedM[chunk * 4 + t];
        float m = -INFINITY;
        for (int i = 0; i < 64; ++i) {
            float l = llog[t * 64 + i];
            m = fmaxf(m, l);
            wbuf[t * 64 + i] = expf(l - fmaxf(M, m));
        }
    }
    __syncthreads();
    float w_t = wbuf[t];
    exg[(size_t)chunk * 256 + t] = w_t;
    red[t] = w_t;
    __syncthreads();
    for (int off = 32; off >= 1; off >>= 1) {
        if ((t & 63) < off) red[t] += red[t + off];
        __syncthreads();
    }
    if ((t & 63) == 0) S_w[chunk * 4 + (t >> 6)] = red[t];
    // column-parallel S_wx: thread (g,rs) covers rows rs*16..+15 (all in sub rs>>2)
    float acc[8];
    #pragma unroll
    for (int e = 0; e < 8; ++e) acc[e] = 0.f;
    size_t base = (size_t)chunk * 256 * DCH;
    for (int i = 0; i < 16; ++i) {
        int row = rs * 16 + i;
        float w = wbuf[row];
        float4 a  = *(const float4*)(x + base + (size_t)row * DCH + g * 8);
        float4 b4 = *(const float4*)(x + base + (size_t)row * DCH + g * 8 + 4);
        acc[0] += w * a.x;  acc[1] += w * a.y;  acc[2] += w * a.z;  acc[3] += w * a.w;
        acc[4] += w * b4.x; acc[5] += w * b4.y; acc[6] += w * b4.z; acc[7] += w * b4.w;
    }
    #pragma unroll
    for (int e = 0; e < 8; ++e) rp[rs * 130 + g * 8 + e] = acc[e];
    __syncthreads();
    #pragma unroll
    for (int k = 0; k < 2; ++k) {
        int idx = k * 256 + t;                 // 4 subs x 128 ch
        int sub = idx >> 7, c = idx & 127;
        float sm = rp[(sub * 4 + 0) * 130 + c] + rp[(sub * 4 + 1) * 130 + c] +
                   rp[(sub * 4 + 2) * 130 + c] + rp[(sub * 4 + 3) * 130 + c];
        S_wx[((size_t)chunk * 4 + sub) * DCH + c] = sm;
    }
}

// ---------------- Stage 4: exclusive prefix sums over sub-chunks (per batch) ----------------
__global__ __launch_bounds__(128) void k_seed_sums(const float* __restrict__ S_w,
                                                   const float* __restrict__ S_wx,
                                                   float* __restrict__ sS_w,
                                                   float* __restrict__ sS_wx) {
    int b = blockIdx.x, t = threadIdx.x;
    float accv = 0.f, accs = 0.f;
    for (int s = 0; s < 512; ++s) {
        int id = b * 512 + s;
        if (t == 0) sS_w[id] = accs;
        accs += S_w[id];
        sS_wx[(size_t)id * DCH + t] = accv;
        accv += S_wx[(size_t)id * DCH + t];
    }
}

// ---------------- zero the halo rows of P ----------------
__global__ __launch_bounds__(256) void k_zero_pad(unsigned short* __restrict__ P) {
    int n = blockIdx.x, t = threadIdx.x;
    for (int i = t; i < 1024; i += 256) {
        int rr = i >> 7;                       // 0..7
        int row = (rr < 2) ? rr : 512 + rr;    // rows 0,1,514..519
        P[(n * PH + row) * DCH + (i & 127)] = 0;
    }
}

// ---------------- Stage 5: apply scan -> prefix_x, write bf16 padded P ----------------
// One wave per 64-row sub-chunk; lane owns a channel pair; fp32 x input.
__global__ __launch_bounds__(128) void k_apply(const float* __restrict__ x,
                                               const float* __restrict__ exg,
                                               const float* __restrict__ sS_w,
                                               const float* __restrict__ sS_wx,
                                               unsigned short* __restrict__ P) {
    int t = threadIdx.x, w = t >> 6, lane = t & 63;
    int s = blockIdx.x * 2 + w;                // sub-chunk id
    int b = s >> 9, sb = s & 511;
    __shared__ float e2[128];
    e2[t] = exg[(size_t)blockIdx.x * 128 + t]; // both waves' w values
    float2 axx = *(const float2*)(sS_wx + (size_t)s * DCH + 2 * lane);
    float aex = sS_w[s];
    __syncthreads();
    const float* es = e2 + w * 64;
    int pib0 = sb * 64;
    int n = b * 64 + (pib0 >> 9);
    int row0 = (pib0 & 511) + 2;
    const float* xp = x + ((size_t)b * LSEQ + pib0) * DCH + 2 * lane;
    unsigned short* pp = P + ((size_t)n * PH + row0) * DCH + 2 * lane;
    for (int j = 0; j < 64; ++j) {
        float e = es[j];
        aex += e;
        float2 xv = *(const float2*)xp;
        axx.x += e * xv.x;
        axx.y += e * xv.y;
        float inv = 1.f / aex;
        unsigned pk = ((unsigned)f2bf(axx.y * inv + xv.y) << 16) | f2bf(axx.x * inv + xv.x);
        *(unsigned*)pp = pk;
        xp += DCH;
        pp += DCH;
    }
}

// ---------------- weight repack: W2t[o][kn*128+i] = conv_w[o][i][kn], bf16 ----------------
__global__ __launch_bounds__(256) void k_w2t(const float* __restrict__ conv_w,
                                             unsigned short* __restrict__ W2t) {
    int idx = blockIdx.x * 256 + threadIdx.x;  // 128*768 = 98304
    if (idx < 128 * 768) {
        int o = idx / 768, kk = idx % 768;
        int kn = kk >> 7, i = kk & 127;
        W2t[idx] = f2bf(conv_w[(o * 128 + i) * 6 + kn]);
    }
}

// ---------------- Stage 6: conv as bf16 MFMA GEMM (128x128 tile, K=768) ----------------
// global_load_lds DMA staging, XOR-swizzled at the DMA *source* so the unpadded
// LDS image reads conflict-free. LDS: A[128][64] @0, B[128][64] @16KB (ushort),
// epilogue C-stage reuses the whole buffer at stride 136.
__global__ __launch_bounds__(256) void k_conv(const unsigned short* __restrict__ P,
                                              const unsigned short* __restrict__ W2t,
                                              const float* __restrict__ conv_b,
                                              unsigned short* __restrict__ convout) {
    int n = blockIdx.x >> 2;
    int h0 = (blockIdx.x & 3) * 128;
    __shared__ __align__(16) unsigned short lds[128 * 136];  // 34,816 B (>= 32 KB A+B)
    char* ldsA = (char*)lds;
    char* ldsB = (char*)lds + 16384;
    int t = threadIdx.x;
    int wave = t >> 6, lane = t & 63;
    f32x4 acc[4][4] = {};
    const unsigned short* Pn = P + (size_t)n * PH * DCH;
    int wm = (wave >> 1) * 64, wn = (wave & 1) * 64;
    int rdma = (lane >> 3);        // row-within-8 handled per DMA instr
    int cpos = lane & 7;           // LDS chunk position this lane fills

    for (int kt = 0; kt < 12; ++kt) {
        int kn = kt >> 1;              // neighbor offset 0..5
        int c0 = (kt & 1) * 64;        // channel slice 0 or 64
        __syncthreads();   // all waves done reading LDS for kt-1
        #pragma unroll
        for (int j = 0; j < 4; ++j) {
            int r = (wave * 4 + j) * 8 + rdma;          // LDS row 0..127
            int gr = h0 + kn + r;                       // global padded row
            int csrcA = cpos ^ (gr & 7);                // source-side swizzle
            async_copy16(Pn + (size_t)gr * DCH + c0 + csrcA * 8,
                         ldsA + (wave * 4 + j) * 1024 + lane * 16);
            int csrcB = cpos ^ (r & 7);
            async_copy16(W2t + (size_t)r * 768 + kt * 64 + csrcB * 8,
                         ldsB + (wave * 4 + j) * 1024 + lane * 16);
        }
        __syncthreads();   // drains vmcnt(0): DMA complete
        #pragma unroll
        for (int ks = 0; ks < 2; ++ks) {
            bf16x8 af[4], bfr[4];
            #pragma unroll
            for (int mi = 0; mi < 4; ++mi) {
                int rA = wm + mi * 16 + (lane & 15);
                int pA = (ks * 4 + (lane >> 4)) ^ ((kn + rA) & 7);
                af[mi] = *(const bf16x8*)(ldsA + rA * 128 + pA * 16);
            }
            #pragma unroll
            for (int ni = 0; ni < 4; ++ni) {
                int oB = wn + ni * 16 + (lane & 15);
                int pB = (ks * 4 + (lane >> 4)) ^ (oB & 7);
                bfr[ni] = *(const bf16x8*)(ldsB + oB * 128 + pB * 16);
            }
            #pragma unroll
            for (int mi = 0; mi < 4; ++mi)
                #pragma unroll
                for (int ni = 0; ni < 4; ++ni)
                    acc[mi][ni] = __builtin_amdgcn_mfma_f32_16x16x32_bf16(af[mi], bfr[ni],
                                                                          acc[mi][ni], 0, 0, 0);
        }
    }
    __syncthreads();   // all A/B LDS reads complete before C-stage overwrite
    // C/D layout: col=lane&15, row=(lane>>4)*4+reg  [m89-verified]
    #pragma unroll
    for (int mi = 0; mi < 4; ++mi)
        #pragma unroll
        for (int ni = 0; ni < 4; ++ni) {
            int col = wn + ni * 16 + (lane & 15);
            float bias = conv_b[col];
            #pragma unroll
            for (int r = 0; r < 4; ++r) {
                int row = wm + mi * 16 + (lane >> 4) * 4 + r;
                lds[row * 136 + col] = f2bf(acc[mi][ni][r] + bias);
            }
        }
    __syncthreads();
    // coalesced store: 2048 granules of 16 B
    size_t base = (size_t)(n * 512 + h0) * DCH;
    #pragma unroll
    for (int it = 0; it < 8; ++it) {
        int idx = it * 256 + t;
        int row = idx >> 4, g = idx & 15;
        uint4 v = *(const uint4*)(lds + row * 136 + g * 8);
        *(uint4*)(convout + base + (size_t)row * DCH + g * 8) = v;
    }
}

// ---------------- Stage 7 fused: block_repr + a_s, column-parallel uint4 passes ----------------
__global__ __launch_bounds__(256) void k_as(const unsigned short* __restrict__ conv,
                                            float* __restrict__ block_repr,
                                            float* __restrict__ a_s) {
    int n = blockIdx.x, t = threadIdx.x;
    int g = t & 15, rs = t >> 4;
    __shared__ __align__(16) float sp[512 * 17];   // row-partials / rp[16][130] / red scratch
    __shared__ float s[512];
    __shared__ float br[128];
    float* rp = sp;                                 // [16][130] view
    const unsigned short* base = conv + (size_t)n * 512 * DCH;

    // ---- phase 0: column max ----
    float m[8];
    #pragma unroll
    for (int e = 0; e < 8; ++e) m[e] = -INFINITY;
    for (int i = 0; i < 32; ++i) {
        int row = i * 16 + rs;
        uint4 v = *(const uint4*)(base + row * DCH + g * 8);
        unsigned vv[4] = {v.x, v.y, v.z, v.w};
        #pragma unroll
        for (int e = 0; e < 4; ++e) {
            m[2 * e]     = fmaxf(m[2 * e],     bf2f((unsigned short)(vv[e] & 0xffff)));
            m[2 * e + 1] = fmaxf(m[2 * e + 1], bf2f((unsigned short)(vv[e] >> 16)));
        }
    }
    #pragma unroll
    for (int e = 0; e < 8; ++e) rp[rs * 130 + g * 8 + e] = m[e];
    __syncthreads();
    if (t < 128) {
        float bm = rp[t];
        #pragma unroll
        for (int r2 = 1; r2 < 16; ++r2) bm = fmaxf(bm, rp[r2 * 130 + t]);
        br[t] = bm;
        block_repr[n * DCH + t] = bm;
    }
    __syncthreads();

    // ---- phase 1: scores s[row] = (conv[row] . br) * SCALE ----
    float brv[8];
    #pragma unroll
    for (int e = 0; e < 8; ++e) brv[e] = br[g * 8 + e];
    for (int i = 0; i < 32; ++i) {
        int row = i * 16 + rs;
        uint4 v = *(const uint4*)(base + row * DCH + g * 8);
        unsigned vv[4] = {v.x, v.y, v.z, v.w};
        float p = 0.f;
        #pragma unroll
        for (int e = 0; e < 4; ++e) {
            p += bf2f((unsigned short)(vv[e] & 0xffff)) * brv[2 * e];
            p += bf2f((unsigned short)(vv[e] >> 16))    * brv[2 * e + 1];
        }
        sp[row * 17 + g] = p;
    }
    __syncthreads();
    #pragma unroll
    for (int rr = 0; rr < 2; ++rr) {
        int row = t * 2 + rr;
        float p = 0.f;
        #pragma unroll
        for (int j = 0; j < 16; ++j) p += sp[row * 17 + j];
        s[row] = p * SCALE_F;
    }
    __syncthreads();

    // ---- softmax over s[512] (scratch reuses sp after scores consumed) ----
    float* red = sp;
    float mm = fmaxf(s[t], s[t + 256]);
    __syncthreads();          // all score reads of sp done before overwrite
    red[t] = mm;
    __syncthreads();
    for (int off = 128; off > 0; off >>= 1) {
        if (t < off) red[t] = fmaxf(red[t], red[t + off]);
        __syncthreads();
    }
    float smax = red[0];
    __syncthreads();
    float e0 = expf(s[t] - smax), e1 = expf(s[t + 256] - smax);
    red[t] = e0 + e1;
    __syncthreads();
    for (int off = 128; off > 0; off >>= 1) {
        if (t < off) red[t] += red[t + off];
        __syncthreads();
    }
    float inv = 1.f / red[0];
    __syncthreads();
    s[t] = e0 * inv;
    s[t + 256] = e1 * inv;
    __syncthreads();

    // ---- phase 2: weighted sum ----
    float acc[8];
    #pragma unroll
    for (int e = 0; e < 8; ++e) acc[e] = 0.f;
    for (int i = 0; i < 32; ++i) {
        int row = i * 16 + rs;
        float w = s[row];
        uint4 v = *(const uint4*)(base + row * DCH + g * 8);
        unsigned vv[4] = {v.x, v.y, v.z, v.w};
        #pragma unroll
        for (int e = 0; e < 4; ++e) {
            acc[2 * e]     += w * bf2f((unsigned short)(vv[e] & 0xffff));
            acc[2 * e + 1] += w * bf2f((unsigned short)(vv[e] >> 16));
        }
    }
    #pragma unroll
    for (int e = 0; e < 8; ++e) rp[rs * 130 + g * 8 + e] = acc[e];
    __syncthreads();
    if (t < 128) {
        float p = 0.f;
        #pragma unroll
        for (int r2 = 0; r2 < 16; ++r2) p += rp[r2 * 130 + t];
        a_s[n * DCH + t] = p;
    }
}

// ---------------- Stage 8: a_o = attn(block_repr, xbo, xbo), column-parallel ----------------
__global__ __launch_bounds__(256) void k_ao(const unsigned short* __restrict__ P,
                                            const float* __restrict__ block_repr,
                                            float* __restrict__ a_o) {
    int n = blockIdx.x, t = threadIdx.x;
    int g = t & 15, rs = t >> 4;
    int b = n >> 6, c = n & 63;
    __shared__ float br[128];
    __shared__ int rb[128];
    __shared__ __align__(16) float sp[128 * 17];   // scores partials / rp[16][130]
    __shared__ float s[128];
    __shared__ float red[128];
    if (t < 128) {
        br[t] = block_repr[n * DCH + t];
        int pib = (c + 1) * 512 - 64 + t;       // window straddling block end
        pib = min(pib, LSEQ - 1);               // edge-clamp at sequence end
        int n2 = b * 64 + (pib >> 9);
        int row = (pib & 511) + 2;
        rb[t] = (n2 * PH + row) * DCH;
    }
    __syncthreads();
    float brv[8];
    #pragma unroll
    for (int e = 0; e < 8; ++e) brv[e] = br[g * 8 + e];
    #pragma unroll
    for (int r = 0; r < 8; ++r) {
        int row = rs * 8 + r;
        uint4 v = *(const uint4*)(P + rb[row] + g * 8);
        unsigned vv[4] = {v.x, v.y, v.z, v.w};
        float p = 0.f;
        #pragma unroll
        for (int e = 0; e < 4; ++e) {
            p += bf2f((unsigned short)(vv[e] & 0xffff)) * brv[2 * e];
            p += bf2f((unsigned short)(vv[e] >> 16))    * brv[2 * e + 1];
        }
        sp[row * 17 + g] = p;
    }
    __syncthreads();
    if (t < 128) {
        float p = 0.f;
        #pragma unroll
        for (int j = 0; j < 16; ++j) p += sp[t * 17 + j];
        s[t] = p * SCALE_F;
        red[t] = s[t];
    }
    __syncthreads();
    for (int off = 64; off > 0; off >>= 1) {
        if (t < off) red[t] = fmaxf(red[t], red[t + off]);
        __syncthreads();
    }
    float smax = red[0];
    __syncthreads();
    if (t < 128) {
        float e = expf(s[t] - smax);
        s[t] = e;
        red[t] = e;
    }
    __syncthreads();
    for (int off = 64; off > 0; off >>= 1) {
        if (t < off) red[t] += red[t + off];
        __syncthreads();
    }
    float inv = 1.f / red[0];
    __syncthreads();
    if (t < 128) s[t] *= inv;
    __syncthreads();
    float acc[8];
    #pragma unroll
    for (int e = 0; e < 8; ++e) acc[e] = 0.f;
    #pragma unroll
    for (int r = 0; r < 8; ++r) {
        int row = rs * 8 + r;
        float w = s[row];
        uint4 v = *(const uint4*)(P + rb[row] + g * 8);
        unsigned vv[4] = {v.x, v.y, v.z, v.w};
        #pragma unroll
        for (int e = 0; e < 4; ++e) {
            acc[2 * e]     += w * bf2f((unsigned short)(vv[e] & 0xffff));
            acc[2 * e + 1] += w * bf2f((unsigned short)(vv[e] >> 16));
        }
    }
    #pragma unroll
    for (int e = 0; e < 8; ++e) sp[rs * 130 + g * 8 + e] = acc[e];
    __syncthreads();
    if (t < 128) {
        float p = 0.f;
        #pragma unroll
        for (int r2 = 0; r2 < 16; ++r2) p += sp[r2 * 130 + t];
        a_o[n * DCH + t] = p;
    }
}

// ---------------- Stage 9: out = concat(a_s,a_o,br) @ fusion_w + fusion_b (x2 copies) ----------------
__global__ __launch_bounds__(128) void k_fusion(const float* __restrict__ a_s,
                                                const float* __restrict__ a_o,
                                                const float* __restrict__ block_repr,
                                                const float* __restrict__ fusion_w,
                                                const float* __restrict__ fusion_b,
                                                float* __restrict__ out) {
    int n = blockIdx.x, t = threadIdx.x;
    __shared__ float fu[384];
    fu[t] = a_s[n * DCH + t];
    fu[128 + t] = a_o[n * DCH + t];
    fu[256 + t] = block_repr[n * DCH + t];
    __syncthreads();
    float acc = fusion_b[t];
    for (int j = 0; j < 384; j++) acc += fu[j] * fusion_w[j * DCH + t];
    out[n * DCH + t] = acc;
    out[NB * 64 * DCH + n * DCH + t] = acc;   // second tuple element (out, out)
}

extern "C" void kernel_launch(void* const* d_in, const int* in_sizes, int n_in,
                              void* d_out, int out_size, void* d_ws, size_t ws_size,
                              hipStream_t stream) {
    const float* x        = (const float*)d_in[0];
    const float* w_lw     = (const float*)d_in[1];
    const float* b_lw     = (const float*)d_in[2];
    const float* conv_w   = (const float*)d_in[3];
    const float* conv_b   = (const float*)d_in[4];
    const float* fusion_w = (const float*)d_in[5];
    const float* fusion_b = (const float*)d_in[6];
    float* out = (float*)d_out;

    char* ws = (char*)d_ws;
    size_t off = 0;
    auto alloc = [&](size_t bytes) { char* p = ws + off; off += (bytes + 255) & ~(size_t)255; return p; };
    float* logits     = (float*)alloc(NB * LSEQ * 4);
    float* exg        = (float*)alloc(NB * LSEQ * 4);
    float* subM       = (float*)alloc(NSUB * 4);
    float* seedM      = (float*)alloc(NSUB * 4);
    float* S_w        = (float*)alloc(NSUB * 4);
    float* sS_w       = (float*)alloc(NSUB * 4);
    float* S_wx       = (float*)alloc((size_t)NSUB * DCH * 4);
    float* sS_wx      = (float*)alloc((size_t)NSUB * DCH * 4);
    float* block_repr = (float*)alloc(NBLK * DCH * 4);
    float* a_s        = (float*)alloc(NBLK * DCH * 4);
    float* a_o        = (float*)alloc(NBLK * DCH * 4);
    unsigned short* W2t     = (unsigned short*)alloc(128 * 768 * 2);
    unsigned short* P       = (unsigned short*)alloc((size_t)NBLK * PH * DCH * 2);
    unsigned short* convout = (unsigned short*)alloc((size_t)NBLK * 512 * DCH * 2);

    k_zero_pad<<<NBLK, 256, 0, stream>>>(P);
    k_w2t<<<384, 256, 0, stream>>>(conv_w, W2t);
    k_logits2<<<NCHUNK, 256, 0, stream>>>(x, w_lw, b_lw, logits, subM);
    k_seed_max<<<1, 64, 0, stream>>>(subM, seedM);
    k_sums<<<NCHUNK, 256, 0, stream>>>(x, logits, seedM, exg, S_w, S_wx);
    k_seed_sums<<<NB, 128, 0, stream>>>(S_w, S_wx, sS_w, sS_wx);
    k_apply<<<NSUB / 2, 128, 0, stream>>>(x, exg, sS_w, sS_wx, P);
    k_conv<<<NBLK * 4, 256, 0, stream>>>(P, W2t, conv_b, convout);
    k_as<<<NBLK, 256, 0, stream>>>(convout, block_repr, a_s);
    k_ao<<<NBLK, 256, 0, stream>>>(P, block_repr, a_o);
    k_fusion<<<NBLK, 128, 0, stream>>>(a_s, a_o, block_repr, fusion_w, fusion_b, out);
}

// Round 8
// 386.470 us; speedup vs baseline: 1.3517x; 1.3517x over previous
//
#include <hip/hip_runtime.h>
#include <hip/hip_bf16.h>

// Problem constants (reference: D=128, BC=64, BS=512, K=6, OV=128, B=8)
#define NB 8            // batches
#define LSEQ 32768      // BC*BS positions per batch
#define DCH 128         // channels
#define NCHUNK 1024     // 256-row chunks
#define NSUB 4096       // 64-row sub-chunks
#define NBLK 512        // B*BC conv blocks
#define PH 520          // padded rows per block (2 front + 512 + pad, rounded)
#define SCALE_F 0.08838834764831845f

typedef __bf16 bf16x8 __attribute__((ext_vector_type(8)));
typedef float f32x4 __attribute__((ext_vector_type(4)));

__device__ __forceinline__ float bf2f(unsigned short u) {
    return __uint_as_float(((unsigned)u) << 16);
}
__device__ __forceinline__ unsigned short f2bf(float f) {
    unsigned u = __float_as_uint(f);
    u += 0x7fffu + ((u >> 16) & 1u);   // round-to-nearest-even
    return (unsigned short)(u >> 16);
}

// async global->LDS DMA, 16 B per lane; LDS dest = wave-uniform base + lane*16
__device__ __forceinline__ void async_copy16(const void* gsrc, void* ldst) {
    __builtin_amdgcn_global_load_lds(
        (const __attribute__((address_space(1))) unsigned int*)gsrc,
        (__attribute__((address_space(3))) unsigned int*)ldst, 16, 0, 0);
}

// ---------------- Stage 1: logits = silu(x @ w_lw + b); per-64-row-sub max ----------------
// Column-parallel dot (LDS partials), no per-row shuffle trees.
// NOTE (R5/R6 post-mortem): reference weights are w_i = exp(l_i - cummax_i) —
// frozen at insertion, never rescaled. The cummax does NOT cancel. Keep it.
__global__ __launch_bounds__(256) void k_logits2(const float* __restrict__ x,
                                                 const float* __restrict__ w_lw,
                                                 const float* __restrict__ b_lw,
                                                 float* __restrict__ logits,
                                                 float* __restrict__ subM) {
    int chunk = blockIdx.x, t = threadIdx.x;
    int g = t & 15, rs = t >> 4;
    __shared__ float sp[256 * 17];
    __shared__ float red[256];
    float wv[8];
    #pragma unroll
    for (int e = 0; e < 8; ++e) wv[e] = w_lw[g * 8 + e];
    float bb = b_lw[0];
    size_t base = (size_t)chunk * 256 * DCH;
    for (int i = 0; i < 16; ++i) {
        int row = rs * 16 + i;
        float4 a  = *(const float4*)(x + base + (size_t)row * DCH + g * 8);
        float4 b4 = *(const float4*)(x + base + (size_t)row * DCH + g * 8 + 4);
        sp[row * 17 + g] = a.x * wv[0] + a.y * wv[1] + a.z * wv[2] + a.w * wv[3] +
                           b4.x * wv[4] + b4.y * wv[5] + b4.z * wv[6] + b4.w * wv[7];
    }
    __syncthreads();
    float s = bb;
    #pragma unroll
    for (int j = 0; j < 16; ++j) s += sp[t * 17 + j];
    float l = s / (1.f + expf(-s));          // silu
    logits[(size_t)chunk * 256 + t] = l;
    red[t] = l;
    __syncthreads();
    for (int off = 32; off >= 1; off >>= 1) {
        if ((t & 63) < off) red[t] = fmaxf(red[t], red[t + off]);
        __syncthreads();
    }
    if ((t & 63) == 0) subM[chunk * 4 + (t >> 6)] = red[t];
}

// ---------------- Stage 2: exclusive prefix-MAX over 512 subs per batch ----------------
// 3-phase wave scan: lane owns 8 subs; shfl_up inclusive scan; rewalk.
__global__ __launch_bounds__(64) void k_seed_max2(const float* __restrict__ subM,
                                                  float* __restrict__ seedM) {
    int b = blockIdx.x, lane = threadIdx.x;
    const float* src = subM + b * 512;
    float* dst = seedM + b * 512;
    float v[8];
    float m = -INFINITY;
    #pragma unroll
    for (int j = 0; j < 8; ++j) { v[j] = src[lane * 8 + j]; m = fmaxf(m, v[j]); }
    float incl = m;
    #pragma unroll
    for (int off = 1; off < 64; off <<= 1) {
        float o = __shfl_up(incl, off, 64);
        if (lane >= off) incl = fmaxf(incl, o);
    }
    float ex = __shfl_up(incl, 1, 64);
    if (lane == 0) ex = -INFINITY;
    float run = ex;
    #pragma unroll
    for (int j = 0; j < 8; ++j) { dst[lane * 8 + j] = run; run = fmaxf(run, v[j]); }
}

// ---------------- Stage 3: w_i = exp(l_i - max(seedM, cummax_loc)); sub sums ----------------
__global__ __launch_bounds__(256) void k_sums(const float* __restrict__ x,
                                              const float* __restrict__ logits,
                                              const float* __restrict__ seedM,
                                              float* __restrict__ exg,
                                              float* __restrict__ S_w,
                                              float* __restrict__ S_wx) {
    int chunk = blockIdx.x, t = threadIdx.x;
    int g = t & 15, rs = t >> 4;
    __shared__ float llog[256];
    __shared__ float wbuf[256];
    __shared__ float red[256];
    __shared__ float rp[16 * 130];
    llog[t] = logits[(size_t)chunk * 256 + t];
    __syncthreads();
    if (t < 4) {                                // serial 64-deep running max per sub
        float M = seedM[chunk * 4 + t];
        float m = -INFINITY;
        for (int i = 0; i < 64; ++i) {
            float l = llog[t * 64 + i];
            m = fmaxf(m, l);
            wbuf[t * 64 + i] = expf(l - fmaxf(M, m));
        }
    }
    __syncthreads();
    float w_t = wbuf[t];
    exg[(size_t)chunk * 256 + t] = w_t;
    red[t] = w_t;
    __syncthreads();
    for (int off = 32; off >= 1; off >>= 1) {
        if ((t & 63) < off) red[t] += red[t + off];
        __syncthreads();
    }
    if ((t & 63) == 0) S_w[chunk * 4 + (t >> 6)] = red[t];
    // column-parallel S_wx: thread (g,rs) covers rows rs*16..+15 (all in sub rs>>2)
    float acc[8];
    #pragma unroll
    for (int e = 0; e < 8; ++e) acc[e] = 0.f;
    size_t base = (size_t)chunk * 256 * DCH;
    for (int i = 0; i < 16; ++i) {
        int row = rs * 16 + i;
        float w = wbuf[row];
        float4 a  = *(const float4*)(x + base + (size_t)row * DCH + g * 8);
        float4 b4 = *(const float4*)(x + base + (size_t)row * DCH + g * 8 + 4);
        acc[0] += w * a.x;  acc[1] += w * a.y;  acc[2] += w * a.z;  acc[3] += w * a.w;
        acc[4] += w * b4.x; acc[5] += w * b4.y; acc[6] += w * b4.z; acc[7] += w * b4.w;
    }
    #pragma unroll
    for (int e = 0; e < 8; ++e) rp[rs * 130 + g * 8 + e] = acc[e];
    __syncthreads();
    #pragma unroll
    for (int k = 0; k < 2; ++k) {
        int idx = k * 256 + t;                 // 4 subs x 128 ch
        int sub = idx >> 7, c = idx & 127;
        float sm = rp[(sub * 4 + 0) * 130 + c] + rp[(sub * 4 + 1) * 130 + c] +
                   rp[(sub * 4 + 2) * 130 + c] + rp[(sub * 4 + 3) * 130 + c];
        S_wx[((size_t)chunk * 4 + sub) * DCH + c] = sm;
    }
}

// ---------------- Stage 4a: exclusive prefix-SUM of S_w (512/batch), wave scan ----------------
__global__ __launch_bounds__(64) void k_seed_w(const float* __restrict__ S_w,
                                               float* __restrict__ sS_w) {
    int b = blockIdx.x, lane = threadIdx.x;
    const float* src = S_w + b * 512;
    float* dst = sS_w + b * 512;
    float v[8];
    float tot = 0.f;
    #pragma unroll
    for (int j = 0; j < 8; ++j) { v[j] = src[lane * 8 + j]; tot += v[j]; }
    float incl = tot;
    #pragma unroll
    for (int off = 1; off < 64; off <<= 1) {
        float o = __shfl_up(incl, off, 64);
        if (lane >= off) incl += o;
    }
    float ex = __shfl_up(incl, 1, 64);
    if (lane == 0) ex = 0.f;
    float run = ex;
    #pragma unroll
    for (int j = 0; j < 8; ++j) { dst[lane * 8 + j] = run; run += v[j]; }
}

// ---------------- Stage 4b: exclusive prefix-SUM of S_wx per channel, 3-phase ----------------
// block = (batch, 16-channel group); thread = (segment of 32 subs, channel)
__global__ __launch_bounds__(256) void k_seed_sums2(const float* __restrict__ S_wx,
                                                    float* __restrict__ sS_wx) {
    int b = blockIdx.x >> 3, cg = blockIdx.x & 7;
    int t = threadIdx.x;
    int cl = t & 15, seg = t >> 4;
    int c = cg * 16 + cl;
    __shared__ float tots[16][17];
    const float* src = S_wx + (size_t)b * 512 * DCH + c;
    float* dst = sS_wx + (size_t)b * 512 * DCH + c;
    int s0 = seg * 32;
    float tot = 0.f;
    for (int j = 0; j < 32; ++j) tot += src[(size_t)(s0 + j) * DCH];
    tots[seg][cl] = tot;
    __syncthreads();
    if (t < 16) {
        float run = 0.f;
        for (int s = 0; s < 16; ++s) { float tmp = tots[s][t]; tots[s][t] = run; run += tmp; }
    }
    __syncthreads();
    float run = tots[seg][cl];
    for (int j = 0; j < 32; ++j) {
        float val = src[(size_t)(s0 + j) * DCH];
        dst[(size_t)(s0 + j) * DCH] = run;
        run += val;
    }
}

// ---------------- zero the halo rows of P ----------------
__global__ __launch_bounds__(256) void k_zero_pad(unsigned short* __restrict__ P) {
    int n = blockIdx.x, t = threadIdx.x;
    for (int i = t; i < 1024; i += 256) {
        int rr = i >> 7;                       // 0..7
        int row = (rr < 2) ? rr : 512 + rr;    // rows 0,1,514..519
        P[(n * PH + row) * DCH + (i & 127)] = 0;
    }
}

// ---------------- Stage 5: apply scan -> prefix_x, write bf16 padded P ----------------
// One wave per 64-row sub-chunk; lane owns a channel pair; fp32 x input.
__global__ __launch_bounds__(128) void k_apply(const float* __restrict__ x,
                                               const float* __restrict__ exg,
                                               const float* __restrict__ sS_w,
                                               const float* __restrict__ sS_wx,
                                               unsigned short* __restrict__ P) {
    int t = threadIdx.x, w = t >> 6, lane = t & 63;
    int s = blockIdx.x * 2 + w;                // sub-chunk id
    int b = s >> 9, sb = s & 511;
    __shared__ float e2[128];
    e2[t] = exg[(size_t)blockIdx.x * 128 + t]; // both waves' w values
    float2 axx = *(const float2*)(sS_wx + (size_t)s * DCH + 2 * lane);
    float aex = sS_w[s];
    __syncthreads();
    const float* es = e2 + w * 64;
    int pib0 = sb * 64;
    int n = b * 64 + (pib0 >> 9);
    int row0 = (pib0 & 511) + 2;
    const float* xp = x + ((size_t)b * LSEQ + pib0) * DCH + 2 * lane;
    unsigned short* pp = P + ((size_t)n * PH + row0) * DCH + 2 * lane;
    for (int j = 0; j < 64; ++j) {
        float e = es[j];
        aex += e;
        float2 xv = *(const float2*)xp;
        axx.x += e * xv.x;
        axx.y += e * xv.y;
        float inv = 1.f / aex;
        unsigned pk = ((unsigned)f2bf(axx.y * inv + xv.y) << 16) | f2bf(axx.x * inv + xv.x);
        *(unsigned*)pp = pk;
        xp += DCH;
        pp += DCH;
    }
}

// ---------------- weight repack: W2t[o][kn*128+i] = conv_w[o][i][kn], bf16 ----------------
__global__ __launch_bounds__(256) void k_w2t(const float* __restrict__ conv_w,
                                             unsigned short* __restrict__ W2t) {
    int idx = blockIdx.x * 256 + threadIdx.x;  // 128*768 = 98304
    if (idx < 128 * 768) {
        int o = idx / 768, kk = idx % 768;
        int kn = kk >> 7, i = kk & 127;
        W2t[idx] = f2bf(conv_w[(o * 128 + i) * 6 + kn]);
    }
}

// ---------------- Stage 6: conv as bf16 MFMA GEMM (128x128 tile, K=768) ----------------
// global_load_lds DMA staging, XOR-swizzled at the DMA *source* so the unpadded
// LDS image reads conflict-free. LDS: A[128][64] @0, B[128][64] @16KB (ushort),
// epilogue C-stage reuses the whole buffer at stride 136.
__global__ __launch_bounds__(256) void k_conv(const unsigned short* __restrict__ P,
                                              const unsigned short* __restrict__ W2t,
                                              const float* __restrict__ conv_b,
                                              unsigned short* __restrict__ convout) {
    int n = blockIdx.x >> 2;
    int h0 = (blockIdx.x & 3) * 128;
    __shared__ __align__(16) unsigned short lds[128 * 136];  // 34,816 B (>= 32 KB A+B)
    char* ldsA = (char*)lds;
    char* ldsB = (char*)lds + 16384;
    int t = threadIdx.x;
    int wave = t >> 6, lane = t & 63;
    f32x4 acc[4][4] = {};
    const unsigned short* Pn = P + (size_t)n * PH * DCH;
    int wm = (wave >> 1) * 64, wn = (wave & 1) * 64;
    int rdma = (lane >> 3);        // row-within-8 handled per DMA instr
    int cpos = lane & 7;           // LDS chunk position this lane fills

    for (int kt = 0; kt < 12; ++kt) {
        int kn = kt >> 1;              // neighbor offset 0..5
        int c0 = (kt & 1) * 64;        // channel slice 0 or 64
        __syncthreads();   // all waves done reading LDS for kt-1
        #pragma unroll
        for (int j = 0; j < 4; ++j) {
            int r = (wave * 4 + j) * 8 + rdma;          // LDS row 0..127
            int gr = h0 + kn + r;                       // global padded row
            int csrcA = cpos ^ (gr & 7);                // source-side swizzle
            async_copy16(Pn + (size_t)gr * DCH + c0 + csrcA * 8,
                         ldsA + (wave * 4 + j) * 1024 + lane * 16);
            int csrcB = cpos ^ (r & 7);
            async_copy16(W2t + (size_t)r * 768 + kt * 64 + csrcB * 8,
                         ldsB + (wave * 4 + j) * 1024 + lane * 16);
        }
        __syncthreads();   // drains vmcnt(0): DMA complete
        #pragma unroll
        for (int ks = 0; ks < 2; ++ks) {
            bf16x8 af[4], bfr[4];
            #pragma unroll
            for (int mi = 0; mi < 4; ++mi) {
                int rA = wm + mi * 16 + (lane & 15);
                int pA = (ks * 4 + (lane >> 4)) ^ ((kn + rA) & 7);
                af[mi] = *(const bf16x8*)(ldsA + rA * 128 + pA * 16);
            }
            #pragma unroll
            for (int ni = 0; ni < 4; ++ni) {
                int oB = wn + ni * 16 + (lane & 15);
                int pB = (ks * 4 + (lane >> 4)) ^ (oB & 7);
                bfr[ni] = *(const bf16x8*)(ldsB + oB * 128 + pB * 16);
            }
            #pragma unroll
            for (int mi = 0; mi < 4; ++mi)
                #pragma unroll
                for (int ni = 0; ni < 4; ++ni)
                    acc[mi][ni] = __builtin_amdgcn_mfma_f32_16x16x32_bf16(af[mi], bfr[ni],
                                                                          acc[mi][ni], 0, 0, 0);
        }
    }
    __syncthreads();   // all A/B LDS reads complete before C-stage overwrite
    // C/D layout: col=lane&15, row=(lane>>4)*4+reg  [m89-verified]
    #pragma unroll
    for (int mi = 0; mi < 4; ++mi)
        #pragma unroll
        for (int ni = 0; ni < 4; ++ni) {
            int col = wn + ni * 16 + (lane & 15);
            float bias = conv_b[col];
            #pragma unroll
            for (int r = 0; r < 4; ++r) {
                int row = wm + mi * 16 + (lane >> 4) * 4 + r;
                lds[row * 136 + col] = f2bf(acc[mi][ni][r] + bias);
            }
        }
    __syncthreads();
    // coalesced store: 2048 granules of 16 B
    size_t base = (size_t)(n * 512 + h0) * DCH;
    #pragma unroll
    for (int it = 0; it < 8; ++it) {
        int idx = it * 256 + t;
        int row = idx >> 4, g = idx & 15;
        uint4 v = *(const uint4*)(lds + row * 136 + g * 8);
        *(uint4*)(convout + base + (size_t)row * DCH + g * 8) = v;
    }
}

// ---------------- Stage 7 fused: block_repr + a_s, column-parallel uint4 passes ----------------
__global__ __launch_bounds__(256) void k_as(const unsigned short* __restrict__ conv,
                                            float* __restrict__ block_repr,
                                            float* __restrict__ a_s) {
    int n = blockIdx.x, t = threadIdx.x;
    int g = t & 15, rs = t >> 4;
    __shared__ __align__(16) float sp[512 * 17];   // row-partials / rp[16][130] / red scratch
    __shared__ float s[512];
    __shared__ float br[128];
    float* rp = sp;                                 // [16][130] view
    const unsigned short* base = conv + (size_t)n * 512 * DCH;

    // ---- phase 0: column max ----
    float m[8];
    #pragma unroll
    for (int e = 0; e < 8; ++e) m[e] = -INFINITY;
    for (int i = 0; i < 32; ++i) {
        int row = i * 16 + rs;
        uint4 v = *(const uint4*)(base + row * DCH + g * 8);
        unsigned vv[4] = {v.x, v.y, v.z, v.w};
        #pragma unroll
        for (int e = 0; e < 4; ++e) {
            m[2 * e]     = fmaxf(m[2 * e],     bf2f((unsigned short)(vv[e] & 0xffff)));
            m[2 * e + 1] = fmaxf(m[2 * e + 1], bf2f((unsigned short)(vv[e] >> 16)));
        }
    }
    #pragma unroll
    for (int e = 0; e < 8; ++e) rp[rs * 130 + g * 8 + e] = m[e];
    __syncthreads();
    if (t < 128) {
        float bm = rp[t];
        #pragma unroll
        for (int r2 = 1; r2 < 16; ++r2) bm = fmaxf(bm, rp[r2 * 130 + t]);
        br[t] = bm;
        block_repr[n * DCH + t] = bm;
    }
    __syncthreads();

    // ---- phase 1: scores s[row] = (conv[row] . br) * SCALE ----
    float brv[8];
    #pragma unroll
    for (int e = 0; e < 8; ++e) brv[e] = br[g * 8 + e];
    for (int i = 0; i < 32; ++i) {
        int row = i * 16 + rs;
        uint4 v = *(const uint4*)(base + row * DCH + g * 8);
        unsigned vv[4] = {v.x, v.y, v.z, v.w};
        float p = 0.f;
        #pragma unroll
        for (int e = 0; e < 4; ++e) {
            p += bf2f((unsigned short)(vv[e] & 0xffff)) * brv[2 * e];
            p += bf2f((unsigned short)(vv[e] >> 16))    * brv[2 * e + 1];
        }
        sp[row * 17 + g] = p;
    }
    __syncthreads();
    #pragma unroll
    for (int rr = 0; rr < 2; ++rr) {
        int row = t * 2 + rr;
        float p = 0.f;
        #pragma unroll
        for (int j = 0; j < 16; ++j) p += sp[row * 17 + j];
        s[row] = p * SCALE_F;
    }
    __syncthreads();

    // ---- softmax over s[512] (scratch reuses sp after scores consumed) ----
    float* red = sp;
    float mm = fmaxf(s[t], s[t + 256]);
    __syncthreads();          // all score reads of sp done before overwrite
    red[t] = mm;
    __syncthreads();
    for (int off = 128; off > 0; off >>= 1) {
        if (t < off) red[t] = fmaxf(red[t], red[t + off]);
        __syncthreads();
    }
    float smax = red[0];
    __syncthreads();
    float e0 = expf(s[t] - smax), e1 = expf(s[t + 256] - smax);
    red[t] = e0 + e1;
    __syncthreads();
    for (int off = 128; off > 0; off >>= 1) {
        if (t < off) red[t] += red[t + off];
        __syncthreads();
    }
    float inv = 1.f / red[0];
    __syncthreads();
    s[t] = e0 * inv;
    s[t + 256] = e1 * inv;
    __syncthreads();

    // ---- phase 2: weighted sum ----
    float acc[8];
    #pragma unroll
    for (int e = 0; e < 8; ++e) acc[e] = 0.f;
    for (int i = 0; i < 32; ++i) {
        int row = i * 16 + rs;
        float w = s[row];
        uint4 v = *(const uint4*)(base + row * DCH + g * 8);
        unsigned vv[4] = {v.x, v.y, v.z, v.w};
        #pragma unroll
        for (int e = 0; e < 4; ++e) {
            acc[2 * e]     += w * bf2f((unsigned short)(vv[e] & 0xffff));
            acc[2 * e + 1] += w * bf2f((unsigned short)(vv[e] >> 16));
        }
    }
    #pragma unroll
    for (int e = 0; e < 8; ++e) rp[rs * 130 + g * 8 + e] = acc[e];
    __syncthreads();
    if (t < 128) {
        float p = 0.f;
        #pragma unroll
        for (int r2 = 0; r2 < 16; ++r2) p += rp[r2 * 130 + t];
        a_s[n * DCH + t] = p;
    }
}

// ---------------- Stage 8: a_o = attn(block_repr, xbo, xbo), column-parallel ----------------
__global__ __launch_bounds__(256) void k_ao(const unsigned short* __restrict__ P,
                                            const float* __restrict__ block_repr,
                                            float* __restrict__ a_o) {
    int n = blockIdx.x, t = threadIdx.x;
    int g = t & 15, rs = t >> 4;
    int b = n >> 6, c = n & 63;
    __shared__ float br[128];
    __shared__ int rb[128];
    __shared__ __align__(16) float sp[128 * 17];   // scores partials / rp[16][130]
    __shared__ float s[128];
    __shared__ float red[128];
    if (t < 128) {
        br[t] = block_repr[n * DCH + t];
        int pib = (c + 1) * 512 - 64 + t;       // window straddling block end
        pib = min(pib, LSEQ - 1);               // edge-clamp at sequence end
        int n2 = b * 64 + (pib >> 9);
        int row = (pib & 511) + 2;
        rb[t] = (n2 * PH + row) * DCH;
    }
    __syncthreads();
    float brv[8];
    #pragma unroll
    for (int e = 0; e < 8; ++e) brv[e] = br[g * 8 + e];
    #pragma unroll
    for (int r = 0; r < 8; ++r) {
        int row = rs * 8 + r;
        uint4 v = *(const uint4*)(P + rb[row] + g * 8);
        unsigned vv[4] = {v.x, v.y, v.z, v.w};
        float p = 0.f;
        #pragma unroll
        for (int e = 0; e < 4; ++e) {
            p += bf2f((unsigned short)(vv[e] & 0xffff)) * brv[2 * e];
            p += bf2f((unsigned short)(vv[e] >> 16))    * brv[2 * e + 1];
        }
        sp[row * 17 + g] = p;
    }
    __syncthreads();
    if (t < 128) {
        float p = 0.f;
        #pragma unroll
        for (int j = 0; j < 16; ++j) p += sp[t * 17 + j];
        s[t] = p * SCALE_F;
        red[t] = s[t];
    }
    __syncthreads();
    for (int off = 64; off > 0; off >>= 1) {
        if (t < off) red[t] = fmaxf(red[t], red[t + off]);
        __syncthreads();
    }
    float smax = red[0];
    __syncthreads();
    if (t < 128) {
        float e = expf(s[t] - smax);
        s[t] = e;
        red[t] = e;
    }
    __syncthreads();
    for (int off = 64; off > 0; off >>= 1) {
        if (t < off) red[t] += red[t + off];
        __syncthreads();
    }
    float inv = 1.f / red[0];
    __syncthreads();
    if (t < 128) s[t] *= inv;
    __syncthreads();
    float acc[8];
    #pragma unroll
    for (int e = 0; e < 8; ++e) acc[e] = 0.f;
    #pragma unroll
    for (int r = 0; r < 8; ++r) {
        int row = rs * 8 + r;
        float w = s[row];
        uint4 v = *(const uint4*)(P + rb[row] + g * 8);
        unsigned vv[4] = {v.x, v.y, v.z, v.w};
        #pragma unroll
        for (int e = 0; e < 4; ++e) {
            acc[2 * e]     += w * bf2f((unsigned short)(vv[e] & 0xffff));
            acc[2 * e + 1] += w * bf2f((unsigned short)(vv[e] >> 16));
        }
    }
    #pragma unroll
    for (int e = 0; e < 8; ++e) sp[rs * 130 + g * 8 + e] = acc[e];
    __syncthreads();
    if (t < 128) {
        float p = 0.f;
        #pragma unroll
        for (int r2 = 0; r2 < 16; ++r2) p += sp[r2 * 130 + t];
        a_o[n * DCH + t] = p;
    }
}

// ---------------- Stage 9: out = concat(a_s,a_o,br) @ fusion_w + fusion_b (x2 copies) ----------------
__global__ __launch_bounds__(128) void k_fusion(const float* __restrict__ a_s,
                                                const float* __restrict__ a_o,
                                                const float* __restrict__ block_repr,
                                                const float* __restrict__ fusion_w,
                                                const float* __restrict__ fusion_b,
                                                float* __restrict__ out) {
    int n = blockIdx.x, t = threadIdx.x;
    __shared__ float fu[384];
    fu[t] = a_s[n * DCH + t];
    fu[128 + t] = a_o[n * DCH + t];
    fu[256 + t] = block_repr[n * DCH + t];
    __syncthreads();
    float acc = fusion_b[t];
    for (int j = 0; j < 384; j++) acc += fu[j] * fusion_w[j * DCH + t];
    out[n * DCH + t] = acc;
    out[NB * 64 * DCH + n * DCH + t] = acc;   // second tuple element (out, out)
}

extern "C" void kernel_launch(void* const* d_in, const int* in_sizes, int n_in,
                              void* d_out, int out_size, void* d_ws, size_t ws_size,
                              hipStream_t stream) {
    const float* x        = (const float*)d_in[0];
    const float* w_lw     = (const float*)d_in[1];
    const float* b_lw     = (const float*)d_in[2];
    const float* conv_w   = (const float*)d_in[3];
    const float* conv_b   = (const float*)d_in[4];
    const float* fusion_w = (const float*)d_in[5];
    const float* fusion_b = (const float*)d_in[6];
    float* out = (float*)d_out;

    char* ws = (char*)d_ws;
    size_t off = 0;
    auto alloc = [&](size_t bytes) { char* p = ws + off; off += (bytes + 255) & ~(size_t)255; return p; };
    float* logits     = (float*)alloc(NB * LSEQ * 4);
    float* exg        = (float*)alloc(NB * LSEQ * 4);
    float* subM       = (float*)alloc(NSUB * 4);
    float* seedM      = (float*)alloc(NSUB * 4);
    float* S_w        = (float*)alloc(NSUB * 4);
    float* sS_w       = (float*)alloc(NSUB * 4);
    float* S_wx       = (float*)alloc((size_t)NSUB * DCH * 4);
    float* sS_wx      = (float*)alloc((size_t)NSUB * DCH * 4);
    float* block_repr = (float*)alloc(NBLK * DCH * 4);
    float* a_s        = (float*)alloc(NBLK * DCH * 4);
    float* a_o        = (float*)alloc(NBLK * DCH * 4);
    unsigned short* W2t     = (unsigned short*)alloc(128 * 768 * 2);
    unsigned short* P       = (unsigned short*)alloc((size_t)NBLK * PH * DCH * 2);
    unsigned short* convout = (unsigned short*)alloc((size_t)NBLK * 512 * DCH * 2);

    k_zero_pad<<<NBLK, 256, 0, stream>>>(P);
    k_w2t<<<384, 256, 0, stream>>>(conv_w, W2t);
    k_logits2<<<NCHUNK, 256, 0, stream>>>(x, w_lw, b_lw, logits, subM);
    k_seed_max2<<<NB, 64, 0, stream>>>(subM, seedM);
    k_sums<<<NCHUNK, 256, 0, stream>>>(x, logits, seedM, exg, S_w, S_wx);
    k_seed_w<<<NB, 64, 0, stream>>>(S_w, sS_w);
    k_seed_sums2<<<NB * 8, 256, 0, stream>>>(S_wx, sS_wx);
    k_apply<<<NSUB / 2, 128, 0, stream>>>(x, exg, sS_w, sS_wx, P);
    k_conv<<<NBLK * 4, 256, 0, stream>>>(P, W2t, conv_b, convout);
    k_as<<<NBLK, 256, 0, stream>>>(convout, block_repr, a_s);
    k_ao<<<NBLK, 256, 0, stream>>>(P, block_repr, a_o);
    k_fusion<<<NBLK, 128, 0, stream>>>(a_s, a_o, block_repr, fusion_w, fusion_b, out);
}